// Round 5
// baseline (363.744 us; speedup 1.0000x reference)
//
#include <hip/hip_runtime.h>

// TrellisLinear: out = (x * su) @ (grid[codes] * scales * sv)
// M=512, K=8192, N=8192, GROUP=128.
// Round 5: fused GEMM with double-buffered LDS, ONE barrier per K-step,
// counted s_waitcnt vmcnt(8) (code loads stay in flight across the barrier),
// BM=256/BN=64/BK=32, one-n-per-lane dequant with v_cvt_pk_bf16_f32.

typedef __attribute__((ext_vector_type(8))) short short8;
typedef __attribute__((ext_vector_type(4))) float f32x4;

__device__ __forceinline__ unsigned short f2bf(float f) {
  unsigned int u = __builtin_bit_cast(unsigned int, f);
  u += 0x7FFFu + ((u >> 16) & 1u);
  return (unsigned short)(u >> 16);
}

__device__ __forceinline__ void gld16(const void* g, void* l) {
  __builtin_amdgcn_global_load_lds(
      (__attribute__((address_space(1))) void*)(g),
      (__attribute__((address_space(3))) void*)(l), 16, 0, 0);
}

// ---------------------------------------------------------------------------
__global__ __launch_bounds__(256) void zero_out(float4* __restrict__ p, int n4) {
  int i = blockIdx.x * 256 + threadIdx.x;
  int stride = gridDim.x * 256;
  for (; i < n4; i += stride) p[i] = float4{0.f, 0.f, 0.f, 0.f};
}

// ---------------------------------------------------------------------------
__global__ __launch_bounds__(256) void convert_x_su(
    const float* __restrict__ x, const float* __restrict__ su,
    unsigned short* __restrict__ xp, int K) {
  int k = blockIdx.x * 2048 + threadIdx.x * 8;
  size_t i = (size_t)blockIdx.y * K + k;
  float4 x0 = *(const float4*)(x + i);
  float4 x1 = *(const float4*)(x + i + 4);
  float4 s0 = *(const float4*)(su + k);
  float4 s1 = *(const float4*)(su + k + 4);
  unsigned int r0 = f2bf(x0.x * s0.x) | ((unsigned int)f2bf(x0.y * s0.y) << 16);
  unsigned int r1 = f2bf(x0.z * s0.z) | ((unsigned int)f2bf(x0.w * s0.w) << 16);
  unsigned int r2 = f2bf(x1.x * s1.x) | ((unsigned int)f2bf(x1.y * s1.y) << 16);
  unsigned int r3 = f2bf(x1.z * s1.z) | ((unsigned int)f2bf(x1.w * s1.w) << 16);
  uint4 o; o.x = r0; o.y = r1; o.z = r2; o.w = r3;
  *(uint4*)(xp + i) = o;
}

// ---------------------------------------------------------------------------
#define BM 256
#define BN 64
#define BK 32
#define KS 4

__global__ __launch_bounds__(256, 3) void gemm_fused(
    const unsigned short* __restrict__ A,   // [M][K] bf16 bits (x*su)
    const int* __restrict__ packed,         // [K][N/2] one byte-code per int32
    const float* __restrict__ gridv,        // [16]
    const float* __restrict__ scales,       // [K/128][N]
    const float* __restrict__ sv,           // [N]
    float* __restrict__ C, int M, int N, int K) {
  __shared__ unsigned short As[2][BM * BK];  // 2 x 16 KB
  __shared__ unsigned short Bs[2][BN * BK];  // 2 x 4 KB
  __shared__ float sS[16 * BN];              // 4 KB: scales*sv per group
  __shared__ float sGd[32];                  // LUT duplicated stride-2

  int t = threadIdx.x;
  int l = t & 63;
  int w = t >> 6;

  // XCD-aware swizzle, mb fastest (m-blocks sharing a packed panel -> same L2)
  int nwg = gridDim.x;                    // 256, divisible by 8
  int bid = blockIdx.x;
  int swz = (bid & 7) * (nwg >> 3) + (bid >> 3);
  int mbs = M / BM;                       // 2
  int mb = swz % mbs;
  int nb = swz / mbs;
  size_t m0 = (size_t)mb * BM;
  size_t n0 = (size_t)nb * BN;
  int kbeg = blockIdx.y * (K / KS);       // 2048-wide K slice
  const int NT = (K / KS) / BK;           // 64 K-steps

  if (t < 16) { float g = gridv[t]; sGd[2 * t] = g; sGd[2 * t + 1] = g; }
  int g0 = kbeg >> 7;
  for (int i = t; i < 16 * BN; i += 256) {
    int g = i >> 6, n = i & 63;
    sS[i] = scales[(size_t)(g0 + g) * N + n0 + n] * sv[n0 + n];
  }
  __syncthreads();

  // ---- A staging (4 gld16/wave, linear LDS dest, pre-swizzled source chunk)
  const unsigned short* Ag = A + m0 * K;
  int arow = l >> 2;                          // row within 16-row group
  int asrc_ch = (l & 3) ^ ((l >> 3) & 3);     // logical chunk for this dest slot
#define STAGE_A(BUF, K0)                                                    \
  {                                                                         \
    _Pragma("unroll") for (int r_ = 0; r_ < 4; ++r_) {                      \
      int gi_ = w * 4 + r_;                                                 \
      int row_ = gi_ * 16 + arow;                                           \
      gld16(Ag + (size_t)row_ * K + (K0) + asrc_ch * 8,                     \
            &As[BUF][gi_ * 512 + l * 8]);                                   \
    }                                                                       \
  }

  // ---- code loads: one n per lane (n = l), k rows w*8..w*8+7
  size_t rs = (size_t)(N >> 1);
  const int* pb = packed + (n0 >> 1) + (l >> 1) + (size_t)(w * 8) * rs;
#define LOAD_CODES(PV, TT)                                                  \
  {                                                                         \
    const int* p_ = pb + (size_t)(kbeg + (TT) * BK) * rs;                   \
    _Pragma("unroll") for (int j_ = 0; j_ < 8; ++j_)                        \
        PV[j_] = p_[(size_t)j_ * rs];                                       \
  }

  // ---- dequant: 8 codes -> 8 bf16 along k -> one ds_write_b128
  int par = l & 1;
  int nsh = par * 4;
  int bw_ch = (w ^ ((l >> 1) & 3)) * 8;   // swizzled chunk (shorts)
#define DEQUANT(PV, BUF, GRP)                                               \
  {                                                                         \
    float an_ = sS[(GRP) * BN + l];                                         \
    unsigned int u_[4];                                                     \
    _Pragma("unroll") for (int q_ = 0; q_ < 4; ++q_) {                      \
      int nib0_ = (PV[2 * q_] >> nsh) & 15;                                 \
      int nib1_ = (PV[2 * q_ + 1] >> nsh) & 15;                             \
      float f0_ = sGd[nib0_ * 2 + par] * an_;                               \
      float f1_ = sGd[nib1_ * 2 + par] * an_;                               \
      asm("v_cvt_pk_bf16_f32 %0, %1, %2" : "=v"(u_[q_]) : "v"(f0_), "v"(f1_)); \
    }                                                                       \
    uint4 vv_; vv_.x = u_[0]; vv_.y = u_[1]; vv_.z = u_[2]; vv_.w = u_[3];  \
    *(uint4*)&Bs[BUF][l * BK + bw_ch] = vv_;                                \
  }

  // ---- MFMA phase (buffer index is a compile-time literal at each use)
  int lr = l & 15, lh = l >> 4;
  int fr_ch = (lh ^ ((lr >> 1) & 3)) << 3;  // swizzled chunk (shorts)
  f32x4 acc[4][4] = {};
#define MFMA_PHASE(BUF)                                                     \
  {                                                                         \
    short8 a_[4], b_[4];                                                    \
    _Pragma("unroll") for (int i_ = 0; i_ < 4; ++i_) {                      \
      int row_ = w * 64 + i_ * 16 + lr;                                     \
      a_[i_] = *(const short8*)&As[BUF][row_ * BK + fr_ch];                 \
    }                                                                       \
    _Pragma("unroll") for (int j_ = 0; j_ < 4; ++j_) {                      \
      int row_ = j_ * 16 + lr;                                              \
      b_[j_] = *(const short8*)&Bs[BUF][row_ * BK + fr_ch];                 \
    }                                                                       \
    _Pragma("unroll") for (int i_ = 0; i_ < 4; ++i_)                        \
        _Pragma("unroll") for (int j_ = 0; j_ < 4; ++j_)                    \
            acc[i_][j_] = __builtin_amdgcn_mfma_f32_16x16x32_bf16(          \
                a_[i_], b_[j_], acc[i_][j_], 0, 0, 0);                      \
  }

  int pv[8], pvn[8];

  // ---- prologue: tile 0 staged+dequanted; pv <- codes(tile 1)
  STAGE_A(0, kbeg);
  __builtin_amdgcn_sched_barrier(0);
  LOAD_CODES(pv, 0);
  DEQUANT(pv, 0, 0);            // compiler inserts the vmcnt wait for pv
  LOAD_CODES(pv, 1);
  asm volatile("s_waitcnt vmcnt(8) lgkmcnt(0)" ::: "memory");
  __builtin_amdgcn_s_barrier();

  // ---- main loop: ITER(t, cur) computes tile t, stages tile t+1,
  //      dequants tile t+1 from PV, loads PVN <- codes(t+2).
#define ITER(T, CUR, PV, PVN)                                               \
  {                                                                         \
    if ((T) + 1 < NT) {                                                     \
      STAGE_A((CUR) ^ 1, kbeg + ((T) + 1) * BK);                            \
      __builtin_amdgcn_sched_barrier(0);                                    \
      int t2_ = ((T) + 2 < NT) ? (T) + 2 : NT - 1;                          \
      LOAD_CODES(PVN, t2_);                                                 \
      DEQUANT(PV, (CUR) ^ 1, ((T) + 1) >> 2);                               \
    }                                                                       \
    MFMA_PHASE(CUR);                                                        \
    asm volatile("s_waitcnt vmcnt(8) lgkmcnt(0)" ::: "memory");             \
    __builtin_amdgcn_s_barrier();                                           \
  }

#pragma unroll 1
  for (int tt = 0; tt < NT; tt += 2) {
    ITER(tt, 0, pv, pvn);
    ITER(tt + 1, 1, pvn, pv);
  }

  // ---- epilogue: C/D layout col=lane&15, row=(lane>>4)*4+r. split-K atomics.
  int lq = l >> 4;
#pragma unroll
  for (int i = 0; i < 4; ++i)
#pragma unroll
    for (int j = 0; j < 4; ++j) {
      size_t row = m0 + w * 64 + i * 16 + lq * 4;
      size_t col = n0 + j * 16 + lr;
#pragma unroll
      for (int r = 0; r < 4; ++r)
        atomicAdd(&C[(row + r) * N + col], acc[i][j][r]);
    }
}

// ---------------------------------------------------------------------------
extern "C" void kernel_launch(void* const* d_in, const int* in_sizes, int n_in,
                              void* d_out, int out_size, void* d_ws, size_t ws_size,
                              hipStream_t stream) {
  const float* x      = (const float*)d_in[0];
  const int*   packed = (const int*)d_in[1];
  const float* gridv  = (const float*)d_in[2];
  const float* scales = (const float*)d_in[3];
  const float* su     = (const float*)d_in[4];
  const float* sv     = (const float*)d_in[5];
  float* out = (float*)d_out;

  int K = in_sizes[4];
  int N = in_sizes[5];
  int M = in_sizes[0] / K;

  unsigned short* xp = (unsigned short*)d_ws;  // 8 MB

  zero_out<<<1024, 256, 0, stream>>>((float4*)out, (M * N) / 4);
  convert_x_su<<<dim3(K / 2048, M), 256, 0, stream>>>(x, su, xp, K);
  int nwg = (M / BM) * (N / BN);               // 256
  gemm_fused<<<dim3(nwg, KS), 256, 0, stream>>>(xp, packed, gridv, scales, sv,
                                                out, M, N, K);
}

// Round 9
// 319.413 us; speedup vs baseline: 1.1388x; 1.1388x over previous
//
#include <hip/hip_runtime.h>

// TrellisLinear: out = (x * su) @ (grid[codes] * scales * sv)
// M=512, K=8192, N=8192, GROUP=128.
// Round 9 (= round 6 resubmit; broker timeouts x3): round-4 fused structure
// (BM=128,BN=128,BK=64, 2 barriers/K-step, split-K=4) + v_cvt_pk_bf16_f32
// dequant (VALU 240->~80 ops/thread/step) + A-staging issued BEFORE dequant
// so the gld16 latency hides under the dequant VALU.

typedef __attribute__((ext_vector_type(8))) short short8;
typedef __attribute__((ext_vector_type(4))) float f32x4;

__device__ __forceinline__ unsigned short f2bf(float f) {
  unsigned int u = __builtin_bit_cast(unsigned int, f);
  u += 0x7FFFu + ((u >> 16) & 1u);
  return (unsigned short)(u >> 16);
}

__device__ __forceinline__ void gld16(const void* g, void* l) {
  __builtin_amdgcn_global_load_lds(
      (__attribute__((address_space(1))) void*)(g),
      (__attribute__((address_space(3))) void*)(l), 16, 0, 0);
}

// ---------------------------------------------------------------------------
__global__ __launch_bounds__(256) void zero_out(float4* __restrict__ p, int n4) {
  int i = blockIdx.x * 256 + threadIdx.x;
  int stride = gridDim.x * 256;
  for (; i < n4; i += stride) p[i] = float4{0.f, 0.f, 0.f, 0.f};
}

// ---------------------------------------------------------------------------
__global__ __launch_bounds__(256) void convert_x_su(
    const float* __restrict__ x, const float* __restrict__ su,
    unsigned short* __restrict__ xp, int K) {
  int k = blockIdx.x * 2048 + threadIdx.x * 8;
  size_t i = (size_t)blockIdx.y * K + k;
  float4 x0 = *(const float4*)(x + i);
  float4 x1 = *(const float4*)(x + i + 4);
  float4 s0 = *(const float4*)(su + k);
  float4 s1 = *(const float4*)(su + k + 4);
  unsigned int r0 = f2bf(x0.x * s0.x) | ((unsigned int)f2bf(x0.y * s0.y) << 16);
  unsigned int r1 = f2bf(x0.z * s0.z) | ((unsigned int)f2bf(x0.w * s0.w) << 16);
  unsigned int r2 = f2bf(x1.x * s1.x) | ((unsigned int)f2bf(x1.y * s1.y) << 16);
  unsigned int r3 = f2bf(x1.z * s1.z) | ((unsigned int)f2bf(x1.w * s1.w) << 16);
  uint4 o; o.x = r0; o.y = r1; o.z = r2; o.w = r3;
  *(uint4*)(xp + i) = o;
}

// ---------------------------------------------------------------------------
#define BM 128
#define BN 128
#define BK 64
#define KSLICES 4

__global__ __launch_bounds__(256, 3) void gemm_fused(
    const unsigned short* __restrict__ A,   // [M][K] bf16 bits (x*su)
    const int* __restrict__ packed,         // [K][N/2] byte codes in int32
    const float* __restrict__ gridv,        // [16]
    const float* __restrict__ scales,       // [K/128][N]
    const float* __restrict__ sv,           // [N]
    float* __restrict__ C, int M, int N, int K) {
  __shared__ unsigned short As[BM * BK];   // 16 KB
  __shared__ unsigned short Bs[BN * BK];   // 16 KB  [n][k], chunk ^= (n&7)
  __shared__ float sS[16 * 128];           // 8 KB   scales*sv for this K-slice
  __shared__ float sGp[32];                // grid duplicated at stride 2

  int t = threadIdx.x;
  int l = t & 63;
  int w = t >> 6;

  // T1 bijective XCD swizzle; m-fastest so the 4 M-blocks sharing a packed
  // panel land on the same XCD's L2.
  int nwg = gridDim.x;              // (N/BN)*(M/BM), divisible by 8
  int bid = blockIdx.x;
  int swz = (bid & 7) * (nwg >> 3) + (bid >> 3);
  int mblocks = M >> 7;
  int mb = swz % mblocks;
  int nb = swz / mblocks;
  size_t m0 = (size_t)mb * BM;
  size_t n0 = (size_t)nb * BN;
  int kbeg = blockIdx.y * (K / KSLICES);
  int kend = kbeg + K / KSLICES;

  // init LUT + scales
  if (t < 16) { float g = gridv[t]; sGp[t * 2] = g; sGp[t * 2 + 1] = g; }
  int g0 = kbeg >> 7;
  for (int i = t; i < 16 * 128; i += 256) {
    int g = i >> 7, n = i & 127;
    sS[i] = scales[(size_t)(g0 + g) * N + n0 + n] * sv[n0 + n];
  }
  __syncthreads();

  const unsigned short* Ag = A + m0 * K;
  size_t rs = (size_t)(N >> 1);
  int c = l;                       // packed int-col -> n = 2c, 2c+1
  int kq = w;                      // wave handles k-rows kq*16..kq*16+15
  const int* pbase = packed + (n0 >> 1) + c + (size_t)(kq * 16) * rs;
  const float* lut = &sGp[l & 1];  // parity-spread 32-bank LUT base

  int srow = t >> 3, sch = t & 7;
  int lr = l & 15, lh = l >> 4;
  int wr = w >> 1, wc = w & 1;
  int nA = 2 * c, nB = 2 * c + 1;

  f32x4 acc[4][4] = {};

  int pv[16];
  {
    const int* p = pbase + (size_t)kbeg * rs;
#pragma unroll
    for (int j = 0; j < 16; ++j) pv[j] = p[(size_t)j * rs];
  }

  for (int k0 = kbeg; k0 < kend; k0 += BK) {
    // ---- A staging FIRST (async, linear dest, pre-swizzled source chunk);
    //      its latency hides under the dequant VALU below.
#pragma unroll
    for (int r = 0; r < 4; ++r) {
      int row = r * 32 + srow;
      int sc = (sch ^ (row & 7)) * 8;
      gld16(Ag + (size_t)row * K + k0 + sc, &As[row * BK + sch * 8]);
    }
    __builtin_amdgcn_sched_barrier(0);  // keep gld16 issue ahead of dequant

    // ---- dequant pv -> Bs (Bs free: barrier at end of previous iteration)
    int gl = (k0 - kbeg) >> 7;
    float2 a2 = *(const float2*)&sS[gl * 128 + nA];  // aLo(n even), aHi(n odd)
#pragma unroll
    for (int q = 0; q < 2; ++q) {
      int ch = kq * 2 + q;
      uint4 va, vb;
      unsigned int* pa = (unsigned int*)&va;
      unsigned int* pbv = (unsigned int*)&vb;
#pragma unroll
      for (int d = 0; d < 4; ++d) {
        int v0 = pv[q * 8 + 2 * d], v1 = pv[q * 8 + 2 * d + 1];
        float w00 = lut[(v0 & 15) << 1] * a2.x;          // n=nA, k even
        float w01 = lut[(v1 & 15) << 1] * a2.x;          // n=nA, k odd
        float w10 = lut[((v0 >> 4) & 15) << 1] * a2.y;   // n=nB, k even
        float w11 = lut[((v1 >> 4) & 15) << 1] * a2.y;   // n=nB, k odd
        asm("v_cvt_pk_bf16_f32 %0, %1, %2" : "=v"(pa[d]) : "v"(w00), "v"(w01));
        asm("v_cvt_pk_bf16_f32 %0, %1, %2" : "=v"(pbv[d]) : "v"(w10), "v"(w11));
      }
      *(uint4*)&Bs[nA * BK + ((ch ^ (nA & 7)) << 3)] = va;
      *(uint4*)&Bs[nB * BK + ((ch ^ (nB & 7)) << 3)] = vb;
    }
    __syncthreads();

    // ---- prefetch next K-step's codes; drains at the end-of-loop barrier,
    //      overlapping HBM/L3 latency with the MFMA phase.
    int pvn[16] = {};
    if (k0 + BK < kend) {
      const int* p = pbase + (size_t)(k0 + BK) * rs;
#pragma unroll
      for (int j = 0; j < 16; ++j) pvn[j] = p[(size_t)j * rs];
    }

    // ---- MFMA phase
#pragma unroll
    for (int kh = 0; kh < 2; ++kh) {
      short8 a[4], b[4];
      int sk = kh * 4 + lh;
#pragma unroll
      for (int i = 0; i < 4; ++i) {
        int row = wr * 64 + i * 16 + lr;
        a[i] = *(const short8*)&As[row * BK + ((sk ^ (row & 7)) << 3)];
      }
#pragma unroll
      for (int j = 0; j < 4; ++j) {
        int row = wc * 64 + j * 16 + lr;
        b[j] = *(const short8*)&Bs[row * BK + ((sk ^ (row & 7)) << 3)];
      }
#pragma unroll
      for (int i = 0; i < 4; ++i)
#pragma unroll
        for (int j = 0; j < 4; ++j)
          acc[i][j] = __builtin_amdgcn_mfma_f32_16x16x32_bf16(a[i], b[j], acc[i][j], 0, 0, 0);
    }
    __syncthreads();

#pragma unroll
    for (int j = 0; j < 16; ++j) pv[j] = pvn[j];
  }

  // ---- epilogue: C/D layout col=lane&15, row=(lane>>4)*4+r. split-K atomics.
#pragma unroll
  for (int i = 0; i < 4; ++i)
#pragma unroll
    for (int j = 0; j < 4; ++j) {
      size_t row = m0 + wr * 64 + i * 16 + lh * 4;
      size_t col = n0 + wc * 64 + j * 16 + lr;
#pragma unroll
      for (int r = 0; r < 4; ++r)
        atomicAdd(&C[(row + r) * N + col], acc[i][j][r]);
    }
}

// ---------------------------------------------------------------------------
extern "C" void kernel_launch(void* const* d_in, const int* in_sizes, int n_in,
                              void* d_out, int out_size, void* d_ws, size_t ws_size,
                              hipStream_t stream) {
  const float* x      = (const float*)d_in[0];
  const int*   packed = (const int*)d_in[1];
  const float* gridv  = (const float*)d_in[2];
  const float* scales = (const float*)d_in[3];
  const float* su     = (const float*)d_in[4];
  const float* sv     = (const float*)d_in[5];
  float* out = (float*)d_out;

  int K = in_sizes[4];
  int N = in_sizes[5];
  int M = in_sizes[0] / K;

  unsigned short* xp = (unsigned short*)d_ws;  // 8 MB

  zero_out<<<1024, 256, 0, stream>>>((float4*)out, (M * N) / 4);
  convert_x_su<<<dim3(K / 2048, M), 256, 0, stream>>>(x, su, xp, K);
  int nwg = (N / BN) * (M / BM);
  gemm_fused<<<dim3(nwg, KSLICES), 256, 0, stream>>>(xp, packed, gridv, scales, sv,
                                                     out, M, N, K);
}